// Round 14
// baseline (357.898 us; speedup 1.0000x reference)
//
#include <hip/hip_runtime.h>

// Problem dims (fixed)
#define B_DIM  2
#define C_DIM  8
#define F_DIM  1024
#define T_DIM  256
#define CH_DIM 32
#define FH_DIM 4096
#define BT_DIM 512   // B*T

typedef __bf16 bf16x8 __attribute__((ext_vector_type(8)));
typedef __bf16 bf16x4 __attribute__((ext_vector_type(4)));
typedef float  f32x4  __attribute__((ext_vector_type(4)));

__device__ __forceinline__ void async16(const void* g, void* l) {
  __builtin_amdgcn_global_load_lds(
      (const __attribute__((address_space(1))) unsigned int*)g,
      (__attribute__((address_space(3))) unsigned int*)l, 16, 0, 0);
}

#define LGKM0_SCHED() do { \
    asm volatile("s_waitcnt lgkmcnt(0)" ::: "memory"); \
    __builtin_amdgcn_sched_barrier(0); } while (0)

// ---------------------------------------------------------------------------
// Kernel 1: LayerNorm over F (per b,c,t) + affine, written TRANSPOSED:
//   hn[c][b*T + t][f]  (bf16)   (unchanged, proven)
// ---------------------------------------------------------------------------
__global__ void ln_kernel(const float* __restrict__ x,
                          const float* __restrict__ lnw,
                          const float* __restrict__ lnb,
                          __bf16* __restrict__ hn) {
  const int tb = blockIdx.x;      // t-chunk of 16
  const int c  = blockIdx.y;
  const int b  = blockIdx.z;
  const int tid = threadIdx.x;
  const int tx = tid & 15, ty = tid >> 4;
  const int t0 = tb * 16;

  const float* xp = x + (size_t)(b * C_DIM + c) * F_DIM * T_DIM;

  float s = 0.f, s2 = 0.f;
  for (int f = ty; f < F_DIM; f += 16) {
    float v = xp[f * T_DIM + t0 + tx];
    s += v; s2 += v * v;
  }
  __shared__ float ps[16][16], ps2[16][16];
  __shared__ float mean_s[16], rstd_s[16];
  ps[ty][tx] = s; ps2[ty][tx] = s2;
  __syncthreads();
  if (tid < 16) {
    float a = 0.f, a2 = 0.f;
    for (int j = 0; j < 16; ++j) { a += ps[j][tid]; a2 += ps2[j][tid]; }
    float mu  = a * (1.0f / F_DIM);
    float var = a2 * (1.0f / F_DIM) - mu * mu;
    mean_s[tid] = mu;
    rstd_s[tid] = rsqrtf(var + 1e-8f);
  }
  __syncthreads();

  __shared__ float tile[64][17];
  __bf16* hp = hn + ((size_t)c * BT_DIM + b * T_DIM + t0) * F_DIM;
  for (int ff = 0; ff < 16; ++ff) {
    const int f0 = ff * 64;
#pragma unroll
    for (int it = 0; it < 4; ++it) {
      int e  = it * 256 + tid;
      int fi = e >> 4, ti = e & 15;
      float v = xp[(f0 + fi) * T_DIM + t0 + ti];
      v = (v - mean_s[ti]) * rstd_s[ti];
      v = v * lnw[c * F_DIM + f0 + fi] + lnb[c * F_DIM + f0 + fi];
      tile[fi][ti] = v;
    }
    __syncthreads();
#pragma unroll
    for (int it = 0; it < 4; ++it) {
      int e  = it * 256 + tid;
      int fx = e & 63, tw = e >> 6;
      hp[(size_t)tw * F_DIM + f0 + fx] = (__bf16)tile[fx][tw];
    }
    __syncthreads();
  }
}

// ---------------------------------------------------------------------------
// Kernel 2: full-N counted-vmcnt GEMM. BM=128 x BN=512 (NO nt twins ->
// A fetched once; L2-miss demand minimized), BK=32.
//   C[m][n] = sum_k A[batch][m][k] * Bt[batch][n][k]
// 512 thr (8 waves 2Mx4N, wave tile 64m x 128n). LDS 112KB:
// A dbuf 2x8KB + B ring-3 x32KB (2-K-tile prefetch distance).
// Per iter: 2 phases x {stage | ds_read | bar | lgkm0 | 16 MFMA | bar}.
// Ledger: p1's writeA counted-waits A(t+1) (vmcnt(4)) which retires exactly
// B(t+1)+A(t+1); B(t+2)4+A(t+2)2 stay in flight across every barrier —
// NEVER drains. Distance-2 A reg-prefetch (issueA after writeA, WAR-safe).
// Per-XCD per-iter working set ~640KB unique -> multi-iter L2 drift window;
// B tile shared by the XCD's same-batch blocks via L2.
// Grid 256 (1/CU): batch = xcd*(32>>MTBITS)+(idx>>MTBITS), mt = idx&(MT-1).
// CT: per-wave LDS-transpose epilogue, 128B-coalesced C^T stores (R12-proven).
// ---------------------------------------------------------------------------
template<int MTBITS, bool CT>
__global__ __launch_bounds__(512, 2)
void gemm_fn(const float* __restrict__ A, const __bf16* __restrict__ Bm,
             __bf16* __restrict__ Co, const int M, const int K) {
  const int NT = K >> 5;                       // BK=32
  const int bid = blockIdx.x;
  const int xcd = bid & 7, idx = bid >> 3;     // idx 0..31
  const int batch = xcd * (32 >> MTBITS) + (idx >> MTBITS);
  const int mt    = idx & ((1 << MTBITS) - 1);

  const int tid = threadIdx.x, lane = tid & 63, wid = tid >> 6;

  const float*  Ab = A  + (size_t)batch * M * K + (size_t)(mt * 128) * K;
  const __bf16* Bb = Bm + (size_t)batch * BT_DIM * K;

  extern __shared__ __align__(16) char smem[];
  __bf16* const AS = (__bf16*)smem;            // 2 x 4096 elems (8KB each)
  __bf16* const BS = (__bf16*)(smem + 16384);  // 3 x 16384 elems (32KB each)

  const int wm = wid >> 2, wn = wid & 3;       // wave tile 64m x 128n
  const int lr = lane & 15, khi = lane >> 4;
  const int rsw = (lr >> 1) & 3;               // A/B read swizzle (R7-proven)

  // B staging (R8-proven): chunk = 16 rows; row-in-chunk = lane>>2
  const int b_s = (lane & 3) ^ ((lane >> 3) & 3);   // pre-swizzled src slot

  f32x4 acc[4][8] = {};
  float4 sa[2];                                // A(t+1) staging regs
  bf16x8 af[4];

  auto issueB2 = [&](int sbuf, int tt, int j0) {
#pragma unroll
    for (int j = j0; j < j0 + 2; ++j) {
      const int chunk = j * 8 + wid;           // 0..31, 16 rows each
      const int r = chunk * 16 + (lane >> 2);
      async16(Bb + (size_t)r * K + (size_t)tt * 32 + b_s * 8,
              BS + sbuf * 16384 + chunk * 512);
    }
  };
  auto issueA1 = [&](int tt, int i) {
    const int c = i * 512 + tid;               // c in [0,1024)
    const int r = c >> 3, q = c & 7;           // row 0..127, 16B chunk 0..7
    sa[i] = *(const float4*)(Ab + (size_t)r * K + (size_t)tt * 32 + q * 4);
  };
  auto writeA1 = [&](int abuf, int i) {
    const int c = i * 512 + tid;
    const int r = c >> 3, q = c & 7;
    const int s = (q >> 1) ^ ((r >> 1) & 3);   // R7-proven swizzle
    bf16x4 v;
    v[0]=(__bf16)sa[i].x; v[1]=(__bf16)sa[i].y; v[2]=(__bf16)sa[i].z; v[3]=(__bf16)sa[i].w;
    *(bf16x4*)(AS + abuf * 4096 + r * 32 + s * 8 + (q & 1) * 4) = v;
  };
  auto readA = [&](int abuf) {
#pragma unroll
    for (int j = 0; j < 4; ++j) {
      const int row = wm * 64 + j * 16 + lr;
      af[j] = *(const bf16x8*)(AS + abuf * 4096 + row * 32 + ((khi ^ rsw) << 3));
    }
  };
  auto readB4 = [&](bf16x8* bq, int rbuf, int np) {
#pragma unroll
    for (int ni = 0; ni < 4; ++ni) {
      const int row = wn * 128 + (np * 4 + ni) * 16 + lr;
      bq[ni] = *(const bf16x8*)(BS + rbuf * 16384 + row * 32 + ((khi ^ rsw) << 3));
    }
  };
  auto mfma16 = [&](const bf16x8* bq, int np) {
    __builtin_amdgcn_s_setprio(1);
#pragma unroll
    for (int j = 0; j < 4; ++j)
#pragma unroll
      for (int n = 0; n < 4; ++n)
        acc[j][np * 4 + n] =
            __builtin_amdgcn_mfma_f32_16x16x32_bf16(af[j], bq[n], acc[j][np * 4 + n], 0, 0, 0);
    __builtin_amdgcn_s_setprio(0);
  };

  // ---- prologue: A(0)->AS[0]; B(0)->ring0; B(1)->ring1; A(1)->sa ----
  issueA1(0, 0); issueA1(0, 1);
  issueB2(0, 0, 0); issueB2(0, 0, 2);
  issueB2(1, 1, 0); issueB2(1, 1, 2);
  writeA1(0, 0); writeA1(0, 1);               // counted wait: A(0) only
  issueA1(1, 0); issueA1(1, 1);               // A(1) -> sa
  asm volatile("s_waitcnt vmcnt(6)" ::: "memory");  // B(0) landed; B(1)+A(1) fly
  LGKM0_SCHED();
  __builtin_amdgcn_s_barrier();

  int cur = 0;
  for (int t = 0; t < NT; ++t) {
    const int rd = t % 3, st = (t + 2) % 3;
    const int tN = (t + 2 < NT) ? t + 2 : NT - 1;
    bf16x8 bq[4];
    // ---- p0: stage B(t+2) j0,j1 | A frags + B n0-3 | 16 MFMA ----
    issueB2(st, tN, 0);
    readA(cur); readB4(bq, rd, 0);
    __builtin_amdgcn_s_barrier(); LGKM0_SCHED();
    mfma16(bq, 0); __builtin_amdgcn_s_barrier();
    // ---- p1: stage B j2,j3 | writeA(t+1) [vmcnt(4): retires B(t+1)+A(t+1)]
    //          + issueA(t+2) | B n4-7 | 16 MFMA ----
    issueB2(st, tN, 2);
    writeA1(cur ^ 1, 0); writeA1(cur ^ 1, 1);
    issueA1(tN, 0); issueA1(tN, 1);
    readB4(bq, rd, 1);
    __builtin_amdgcn_s_barrier(); LGKM0_SCHED();
    mfma16(bq, 1);
    // boundary: NO vmcnt — B(t+2)+A(t+2) stay in flight
    __builtin_amdgcn_s_barrier();
    cur ^= 1;
  }

  // ---- epilogue: C/D map col = lane&15, row = (lane>>4)*4 + reg ----
  const int colc = lane & 15;
  const int rowb = (lane >> 4) * 4;
  if (CT) {
    // per-wave LDS transpose -> 128B-coalesced stores of C^T[n][m]
    __bf16* T = (__bf16*)smem + wid * 1152;     // 16 x 72 per wave
    const int mbase = mt * 128 + wm * 64;
#pragma unroll
    for (int ni = 0; ni < 8; ++ni) {
#pragma unroll
      for (int mi = 0; mi < 4; ++mi)
#pragma unroll
        for (int r = 0; r < 4; ++r)
          T[colc * 72 + mi * 16 + rowb + r] = (__bf16)acc[mi][ni][r];
      __bf16* outp = Co + (size_t)batch * BT_DIM * M
                        + (size_t)(wn * 128 + ni * 16) * M + mbase + lane;
#pragma unroll
      for (int r16 = 0; r16 < 16; ++r16)
        outp[(size_t)r16 * M] = T[r16 * 72 + lane];
    }
  } else {
#pragma unroll
    for (int mi = 0; mi < 4; ++mi) {
#pragma unroll
      for (int ni = 0; ni < 8; ++ni) {
        const int m = mt * 128 + wm * 64 + mi * 16 + rowb;
        const int n = wn * 128 + ni * 16 + colc;
#pragma unroll
        for (int r = 0; r < 4; ++r)
          Co[((size_t)batch * M + m + r) * BT_DIM + n] = (__bf16)acc[mi][ni][r];
      }
    }
  }
}

// ---------------------------------------------------------------------------
// Kernel 3: channel mix 8->32 + squared ReLU. (unchanged)
// ---------------------------------------------------------------------------
__global__ void mix1_kernel(const __bf16* __restrict__ Y1,
                            const float* __restrict__ dw1,
                            __bf16* __restrict__ h2) {
  const int gidx = blockIdx.x * 256 + threadIdx.x;
  const int g8 = gidx & 511, bt = gidx >> 9;
  const int g0 = g8 * 8;

  float y[C_DIM][8];
#pragma unroll
  for (int c = 0; c < C_DIM; ++c) {
    bf16x8 v = *(const bf16x8*)(Y1 + ((size_t)c * BT_DIM + bt) * FH_DIM + g0);
#pragma unroll
    for (int j = 0; j < 8; ++j) y[c][j] = (float)v[j];
  }
  for (int d = 0; d < CH_DIM; ++d) {
    float s[8] = {0.f,0.f,0.f,0.f,0.f,0.f,0.f,0.f};
#pragma unroll
    for (int c = 0; c < C_DIM; ++c) {
      const float wv = dw1[d * C_DIM + c];
#pragma unroll
      for (int j = 0; j < 8; ++j) s[j] += wv * y[c][j];
    }
    bf16x8 o;
#pragma unroll
    for (int j = 0; j < 8; ++j) {
      float r = s[j] > 0.f ? s[j] : 0.f;
      o[j] = (__bf16)(r * r);
    }
    *(bf16x8*)(h2 + ((size_t)d * BT_DIM + bt) * FH_DIM + g0) = o;
  }
}

// ---------------------------------------------------------------------------
// Kernel 4: channel mix 32->8 + residual. (unchanged from R10)
// ---------------------------------------------------------------------------
__global__ void mix2_kernel(const float* __restrict__ x,
                            const __bf16* __restrict__ Y2,
                            const float* __restrict__ dw2,
                            float* __restrict__ out) {
  const int gidx = blockIdx.x * 256 + threadIdx.x;   // < 131072
  const int t4 = gidx & 63;
  const int f  = (gidx >> 6) & 1023;
  const int b  = gidx >> 16;                         // 0..1
  const int t0 = t4 * 4;

  float4 r[C_DIM];
#pragma unroll
  for (int dd = 0; dd < C_DIM; ++dd)
    r[dd] = *(const float4*)(x + ((size_t)(b * C_DIM + dd) * F_DIM + f) * T_DIM + t0);

  for (int d = 0; d < CH_DIM; ++d) {
    bf16x4 v = *(const bf16x4*)(Y2 + ((size_t)d * F_DIM + f) * BT_DIM + b * T_DIM + t0);
    const float v0 = (float)v[0], v1 = (float)v[1], v2 = (float)v[2], v3 = (float)v[3];
#pragma unroll
    for (int dd = 0; dd < C_DIM; ++dd) {
      const float w = dw2[dd * CH_DIM + d];
      r[dd].x += w * v0; r[dd].y += w * v1; r[dd].z += w * v2; r[dd].w += w * v3;
    }
  }
#pragma unroll
  for (int dd = 0; dd < C_DIM; ++dd)
    *(float4*)(out + ((size_t)(b * C_DIM + dd) * F_DIM + f) * T_DIM + t0) = r[dd];
}

// ---------------------------------------------------------------------------
extern "C" void kernel_launch(void* const* d_in, const int* in_sizes, int n_in,
                              void* d_out, int out_size, void* d_ws, size_t ws_size,
                              hipStream_t stream) {
  const float* x   = (const float*)d_in[0];
  const float* lnw = (const float*)d_in[1];
  const float* lnb = (const float*)d_in[2];
  const float* pw1 = (const float*)d_in[3];
  const float* dw1 = (const float*)d_in[4];
  const float* pw2 = (const float*)d_in[5];
  const float* dw2 = (const float*)d_in[6];
  float* out = (float*)d_out;

  char* ws = (char*)d_ws;
  __bf16* hn = (__bf16*)(ws);                    // [C][512][F]    8 MB
  __bf16* Y1 = (__bf16*)(ws + (8ULL << 20));     // [C][512][Fh]  32 MB
  __bf16* h2 = (__bf16*)(ws + (40ULL << 20));    // [Ch][512][Fh] 128 MB
  __bf16* Y2 = (__bf16*)(ws);                    // [Ch][F][512]  32 MB (reuse)

  (void)hipFuncSetAttribute((const void*)gemm_fn<5, true>,
                            hipFuncAttributeMaxDynamicSharedMemorySize, 114688);
  (void)hipFuncSetAttribute((const void*)gemm_fn<3, false>,
                            hipFuncAttributeMaxDynamicSharedMemorySize, 114688);

  ln_kernel<<<dim3(T_DIM / 16, C_DIM, B_DIM), 256, 0, stream>>>(x, lnw, lnb, hn);
  // pw1: per c: [4096 x 1024] @ [1024 x 512]^T -> Y1^T [512][4096]
  gemm_fn<5, true><<<256, 512, 114688, stream>>>(pw1, hn, Y1, FH_DIM, F_DIM);
  mix1_kernel<<<(BT_DIM * (FH_DIM / 8)) / 256, 256, 0, stream>>>(Y1, dw1, h2);
  // pw2: per d: [1024 x 4096] @ [4096 x 512]^T -> Y2 [1024][512]
  gemm_fn<3, false><<<256, 512, 114688, stream>>>(pw2, h2, Y2, F_DIM, FH_DIM);
  mix2_kernel<<<512, 256, 0, stream>>>(x, Y2, dw2, out);
}

// Round 15
// 293.724 us; speedup vs baseline: 1.2185x; 1.2185x over previous
//
#include <hip/hip_runtime.h>

// Problem dims (fixed)
#define B_DIM  2
#define C_DIM  8
#define F_DIM  1024
#define T_DIM  256
#define CH_DIM 32
#define FH_DIM 4096
#define BT_DIM 512   // B*T

typedef __bf16 bf16x8 __attribute__((ext_vector_type(8)));
typedef __bf16 bf16x4 __attribute__((ext_vector_type(4)));
typedef float  f32x4  __attribute__((ext_vector_type(4)));

__device__ __forceinline__ void async16(const void* g, void* l) {
  __builtin_amdgcn_global_load_lds(
      (const __attribute__((address_space(1))) unsigned int*)g,
      (__attribute__((address_space(3))) unsigned int*)l, 16, 0, 0);
}

#define LGKM0_SCHED() do { \
    asm volatile("s_waitcnt lgkmcnt(0)" ::: "memory"); \
    __builtin_amdgcn_sched_barrier(0); } while (0)

// ---------------------------------------------------------------------------
// Kernel 1 (NEW): single-read LayerNorm. Tile 16t x 1024f staged in LDS
// ([t][1028] pad); per-t partial stats accumulated DURING the load; then
// normalize+affine from LDS, write hn[c][b*T+t][f] (bf16) via ushort2.
// Traffic 136 -> 72 MB. Grid (16,8,2) = 256 blocks x 256 thr.
// ---------------------------------------------------------------------------
__global__ void ln_kernel(const float* __restrict__ x,
                          const float* __restrict__ lnw,
                          const float* __restrict__ lnb,
                          __bf16* __restrict__ hn) {
  const int tb = blockIdx.x;      // t-chunk of 16
  const int c  = blockIdx.y;
  const int b  = blockIdx.z;
  const int tid = threadIdx.x;
  const int t0 = tb * 16;

  extern __shared__ __align__(16) float xs[];   // [16][1028]
  __shared__ float ps[16][64], ps2[16][64];
  __shared__ float mean_s[16], rstd_s[16];

  const float* xp = x + (size_t)(b * C_DIM + c) * F_DIM * T_DIM;

  const int fbase = tid >> 2;     // 0..63
  const int tq    = tid & 3;      // 0..3 (t-quad)

  float s0 = 0.f, s1 = 0.f, s2v = 0.f, s3 = 0.f;
  float q0 = 0.f, q1 = 0.f, q2 = 0.f, q3 = 0.f;
#pragma unroll 4
  for (int it = 0; it < 16; ++it) {
    const int f = it * 64 + fbase;
    const float4 v = *(const float4*)(xp + (size_t)f * T_DIM + t0 + tq * 4);
    xs[(tq * 4 + 0) * 1028 + f] = v.x;
    xs[(tq * 4 + 1) * 1028 + f] = v.y;
    xs[(tq * 4 + 2) * 1028 + f] = v.z;
    xs[(tq * 4 + 3) * 1028 + f] = v.w;
    s0 += v.x; q0 += v.x * v.x;
    s1 += v.y; q1 += v.y * v.y;
    s2v += v.z; q2 += v.z * v.z;
    s3 += v.w; q3 += v.w * v.w;
  }
  ps[tq * 4 + 0][fbase] = s0;  ps2[tq * 4 + 0][fbase] = q0;
  ps[tq * 4 + 1][fbase] = s1;  ps2[tq * 4 + 1][fbase] = q1;
  ps[tq * 4 + 2][fbase] = s2v; ps2[tq * 4 + 2][fbase] = q2;
  ps[tq * 4 + 3][fbase] = s3;  ps2[tq * 4 + 3][fbase] = q3;
  __syncthreads();
  if (tid < 16) {
    float a = 0.f, a2 = 0.f;
    for (int j = 0; j < 64; ++j) { a += ps[tid][j]; a2 += ps2[tid][j]; }
    const float mu  = a * (1.0f / F_DIM);
    const float var = a2 * (1.0f / F_DIM) - mu * mu;
    mean_s[tid] = mu;
    rstd_s[tid] = rsqrtf(var + 1e-8f);
  }
  __syncthreads();

  // normalize + affine + write: wave w handles t = w*4+p; lane covers
  // f = j*128 + lane*2 (float2 LDS reads, ushort2 global stores).
  const int wv = tid >> 6, lane = tid & 63;
  const float* lw = lnw + c * F_DIM;
  const float* lb = lnb + c * F_DIM;
#pragma unroll
  for (int p = 0; p < 4; ++p) {
    const int t = wv * 4 + p;
    const float mu = mean_s[t], rs = rstd_s[t];
    __bf16* hp = hn + ((size_t)c * BT_DIM + b * T_DIM + t0 + t) * F_DIM;
#pragma unroll
    for (int j = 0; j < 8; ++j) {
      const int f = j * 128 + lane * 2;
      const float a = xs[t * 1028 + f];
      const float bb = xs[t * 1028 + f + 1];
      const float r0 = (a - mu) * rs * lw[f] + lb[f];
      const float r1 = (bb - mu) * rs * lw[f + 1] + lb[f + 1];
      __bf16 o2[2] = { (__bf16)r0, (__bf16)r1 };
      *(ushort*)nullptr == *(ushort*)nullptr;  // (never executed pattern guard removed)
      *(uint*)(hp + f) = *(uint*)o2;
    }
  }
}

// ---------------------------------------------------------------------------
// Kernel 2: 4-phase counted-vmcnt GEMM (R13-proven, byte-identical).
// BM=256 x BN=256, BK=64, 512 thr (8 waves 2Mx4N, wave tile 128x64).
// LDS 160KB: A dbuf 2x32KB + B ring 3x32KB. Distance-2 A reg-prefetch;
// B ring-3. Boundary has NO vmcnt. Never drains to 0.
// ---------------------------------------------------------------------------
template<int TPB_BITS, bool CT>
__global__ __launch_bounds__(512, 2)
void gemm_4p(const float* __restrict__ A, const __bf16* __restrict__ Bm,
             __bf16* __restrict__ Co, const int M, const int K) {
  const int NT = K >> 6;
  const int bid = blockIdx.x;
  const int xcd = bid & 7, idx = bid >> 3;     // idx 0..31
  const int batch = xcd * (32 >> TPB_BITS) + (idx >> TPB_BITS);
  const int tile  = idx & ((1 << TPB_BITS) - 1);
  const int mt = tile >> 1, nt = tile & 1;

  const int tid = threadIdx.x, lane = tid & 63, wid = tid >> 6;

  const float*  Ab = A  + (size_t)batch * M * K + (size_t)(mt * 256) * K;
  const __bf16* Bb = Bm + (size_t)batch * BT_DIM * K + (size_t)(nt * 256) * K;

  extern __shared__ __align__(16) char smem[];
  __bf16* const AS = (__bf16*)smem;            // 2 x 16384 elems (32KB)
  __bf16* const BS = (__bf16*)(smem + 65536);  // 3 x 16384 elems (32KB)

  const int wm = wid >> 2, wn = wid & 3;       // wave tile 128x64
  const int lr = lane & 15, khi = lane >> 4;
  const int lsw = lr & 7;

  const int b_row = lane >> 3;                 // row within 8-row chunk
  const int b_src = (lane & 7) ^ b_row;        // pre-swizzled 16B source slot

  f32x4 acc[8][4] = {};
  float4 sa[8];
  bf16x8 af[4];

  auto issueB1 = [&](int sbuf, int tt, int j) {
    const int chunk = j * 8 + wid;
    async16(Bb + (size_t)(chunk * 8 + b_row) * K + (size_t)tt * 64 + b_src * 8,
            BS + sbuf * 16384 + chunk * 512);
  };
  auto issueA2 = [&](int tt, int i0) {
#pragma unroll
    for (int i = i0; i < i0 + 2; ++i) {
      const int c = i * 512 + tid;
      sa[i] = *(const float4*)(Ab + (size_t)(c >> 4) * K + (size_t)tt * 64 + (c & 15) * 4);
    }
  };
  auto writeA2 = [&](int abuf, int i0) {
#pragma unroll
    for (int i = i0; i < i0 + 2; ++i) {
      const int c = i * 512 + tid;
      const int r = c >> 4;
      const int s = ((c & 15) >> 1) ^ (r & 7);
      bf16x4 v;
      v[0]=(__bf16)sa[i].x; v[1]=(__bf16)sa[i].y; v[2]=(__bf16)sa[i].z; v[3]=(__bf16)sa[i].w;
      *(bf16x4*)(AS + abuf * 16384 + r * 64 + s * 8 + (c & 1) * 4) = v;
    }
  };
  auto readA = [&](int abuf, int mq, int ks) {
#pragma unroll
    for (int j = 0; j < 4; ++j) {
      const int row = wm * 128 + (mq * 4 + j) * 16 + lr;
      af[j] = *(const bf16x8*)(AS + abuf * 16384 + row * 64 + (((ks << 2) | khi) ^ lsw) * 8);
    }
  };
  auto readB4 = [&](bf16x8* bq, int rbuf, int ks) {
#pragma unroll
    for (int ni = 0; ni < 4; ++ni) {
      const int row = wn * 64 + ni * 16 + lr;
      bq[ni] = *(const bf16x8*)(BS + rbuf * 16384 + row * 64 + (((ks << 2) | khi) ^ lsw) * 8);
    }
  };
  auto mfma16 = [&](const bf16x8* bq, int mq) {
    __builtin_amdgcn_s_setprio(1);
#pragma unroll
    for (int j = 0; j < 4; ++j)
#pragma unroll
      for (int n = 0; n < 4; ++n)
        acc[mq * 4 + j][n] =
            __builtin_amdgcn_mfma_f32_16x16x32_bf16(af[j], bq[n], acc[mq * 4 + j][n], 0, 0, 0);
    __builtin_amdgcn_s_setprio(0);
  };

  // ---- prologue: A(0)->AS[0]; A(1)->sa; B(0)->BS[0]; B(1)->BS[1] ----
  issueA2(0, 0); issueA2(0, 2); issueA2(0, 4); issueA2(0, 6);
  issueB1(0, 0, 0); issueB1(0, 0, 1); issueB1(0, 0, 2); issueB1(0, 0, 3);
  issueB1(1, 1, 0); issueB1(1, 1, 1); issueB1(1, 1, 2); issueB1(1, 1, 3);
  writeA2(0, 0); writeA2(0, 2); writeA2(0, 4); writeA2(0, 6);  // waits A(0) only
  issueA2(1, 0); issueA2(1, 2); issueA2(1, 4); issueA2(1, 6);  // A(1) -> sa
  asm volatile("s_waitcnt vmcnt(12)" ::: "memory");  // B(0) landed; rest in flight
  LGKM0_SCHED();
  __builtin_amdgcn_s_barrier();

  int cur = 0;
  for (int t = 0; t < NT; ++t) {
    const int rd = t % 3, st = (t + 2) % 3;
    const int tN = (t + 2 < NT) ? t + 2 : NT - 1;
    bf16x8 bq[4];
    // ---- p0: stage B(t+2) j0,j1 | frags mq0/ks0 + B ks0 | 16 MFMA ----
    issueB1(st, tN, 0); issueB1(st, tN, 1);
    readA(cur, 0, 0); readB4(bq, rd, 0);
    __builtin_amdgcn_s_barrier(); LGKM0_SCHED();
    mfma16(bq, 0); __builtin_amdgcn_s_barrier();
    // ---- p1: stage B j2,j3 | A frags mq1/ks0 (reuse bq) | 16 MFMA ----
    issueB1(st, tN, 2); issueB1(st, tN, 3);
    readA(cur, 1, 0);
    __builtin_amdgcn_s_barrier(); LGKM0_SCHED();
    mfma16(bq, 1); __builtin_amdgcn_s_barrier();
    // ---- p2: writeA(t+1) c0-3 + issueA(t+2) c0-3 | frags mq0/ks1 + B ks1 ----
    writeA2(cur ^ 1, 0); issueA2(tN, 0);
    writeA2(cur ^ 1, 2); issueA2(tN, 2);
    readA(cur, 0, 1); readB4(bq, rd, 1);
    __builtin_amdgcn_s_barrier(); LGKM0_SCHED();
    mfma16(bq, 0); __builtin_amdgcn_s_barrier();
    // ---- p3: writeA c4-7 + issueA c4-7 | A frags mq1/ks1 | 16 MFMA ----
    writeA2(cur ^ 1, 4); issueA2(tN, 4);
    writeA2(cur ^ 1, 6); issueA2(tN, 6);
    readA(cur, 1, 1);
    __builtin_amdgcn_s_barrier(); LGKM0_SCHED();
    mfma16(bq, 1);
    // boundary: NO vmcnt — prefetches stay in flight across the barrier
    __builtin_amdgcn_s_barrier();
    cur ^= 1;
  }

  // ---- epilogue: C/D map col = lane&15, row = (lane>>4)*4 + reg ----
  const int colc = lane & 15;
  const int rowb = (lane >> 4) * 4;
  if (CT) {
    // per-wave LDS transpose (two 64-row halves) -> coalesced C^T stores
    __bf16* T = (__bf16*)smem + wid * 1152;     // 16 x 72 per wave
#pragma unroll
    for (int h = 0; h < 2; ++h) {
      const int mbase = mt * 256 + wm * 128 + h * 64;
#pragma unroll
      for (int ni = 0; ni < 4; ++ni) {
#pragma unroll
        for (int mi = 0; mi < 4; ++mi)
#pragma unroll
          for (int r = 0; r < 4; ++r)
            T[colc * 72 + mi * 16 + rowb + r] = (__bf16)acc[h * 4 + mi][ni][r];
        __bf16* outp = Co + (size_t)batch * BT_DIM * M
                          + (size_t)(nt * 256 + wn * 64 + ni * 16) * M + mbase + lane;
#pragma unroll
        for (int r16 = 0; r16 < 16; ++r16)
          outp[(size_t)r16 * M] = T[r16 * 72 + lane];
      }
    }
  } else {
#pragma unroll
    for (int mi = 0; mi < 8; ++mi) {
#pragma unroll
      for (int ni = 0; ni < 4; ++ni) {
        const int m = mt * 256 + wm * 128 + mi * 16 + rowb;
        const int n = nt * 256 + wn * 64 + ni * 16 + colc;
#pragma unroll
        for (int r = 0; r < 4; ++r)
          Co[((size_t)batch * M + m + r) * BT_DIM + n] = (__bf16)acc[mi][ni][r];
      }
    }
  }
}

// ---------------------------------------------------------------------------
// Kernel 3: channel mix 8->32 + squared ReLU. (unchanged)
// ---------------------------------------------------------------------------
__global__ void mix1_kernel(const __bf16* __restrict__ Y1,
                            const float* __restrict__ dw1,
                            __bf16* __restrict__ h2) {
  const int gidx = blockIdx.x * 256 + threadIdx.x;
  const int g8 = gidx & 511, bt = gidx >> 9;
  const int g0 = g8 * 8;

  float y[C_DIM][8];
#pragma unroll
  for (int c = 0; c < C_DIM; ++c) {
    bf16x8 v = *(const bf16x8*)(Y1 + ((size_t)c * BT_DIM + bt) * FH_DIM + g0);
#pragma unroll
    for (int j = 0; j < 8; ++j) y[c][j] = (float)v[j];
  }
  for (int d = 0; d < CH_DIM; ++d) {
    float s[8] = {0.f,0.f,0.f,0.f,0.f,0.f,0.f,0.f};
#pragma unroll
    for (int c = 0; c < C_DIM; ++c) {
      const float wv = dw1[d * C_DIM + c];
#pragma unroll
      for (int j = 0; j < 8; ++j) s[j] += wv * y[c][j];
    }
    bf16x8 o;
#pragma unroll
    for (int j = 0; j < 8; ++j) {
      float r = s[j] > 0.f ? s[j] : 0.f;
      o[j] = (__bf16)(r * r);
    }
    *(bf16x8*)(h2 + ((size_t)d * BT_DIM + bt) * FH_DIM + g0) = o;
  }
}

// ---------------------------------------------------------------------------
// Kernel 4: channel mix 32->8 + residual. (unchanged)
// ---------------------------------------------------------------------------
__global__ void mix2_kernel(const float* __restrict__ x,
                            const __bf16* __restrict__ Y2,
                            const float* __restrict__ dw2,
                            float* __restrict__ out) {
  const int gidx = blockIdx.x * 256 + threadIdx.x;   // < 131072
  const int t4 = gidx & 63;
  const int f  = (gidx >> 6) & 1023;
  const int b  = gidx >> 16;                         // 0..1
  const int t0 = t4 * 4;

  float4 r[C_DIM];
#pragma unroll
  for (int dd = 0; dd < C_DIM; ++dd)
    r[dd] = *(const float4*)(x + ((size_t)(b * C_DIM + dd) * F_DIM + f) * T_DIM + t0);

  for (int d = 0; d < CH_DIM; ++d) {
    bf16x4 v = *(const bf16x4*)(Y2 + ((size_t)d * F_DIM + f) * BT_DIM + b * T_DIM + t0);
    const float v0 = (float)v[0], v1 = (float)v[1], v2 = (float)v[2], v3 = (float)v[3];
#pragma unroll
    for (int dd = 0; dd < C_DIM; ++dd) {
      const float w = dw2[dd * CH_DIM + d];
      r[dd].x += w * v0; r[dd].y += w * v1; r[dd].z += w * v2; r[dd].w += w * v3;
    }
  }
#pragma unroll
  for (int dd = 0; dd < C_DIM; ++dd)
    *(float4*)(out + ((size_t)(b * C_DIM + dd) * F_DIM + f) * T_DIM + t0) = r[dd];
}

// ---------------------------------------------------------------------------
extern "C" void kernel_launch(void* const* d_in, const int* in_sizes, int n_in,
                              void* d_out, int out_size, void* d_ws, size_t ws_size,
                              hipStream_t stream) {
  const float* x   = (const float*)d_in[0];
  const float* lnw = (const float*)d_in[1];
  const float* lnb = (const float*)d_in[2];
  const float* pw1 = (const float*)d_in[3];
  const float* dw1 = (const float*)d_in[4];
  const float* pw2 = (const float*)d_in[5];
  const float* dw2 = (const float*)d_in[6];
  float* out = (float*)d_out;

  char* ws = (char*)d_ws;
  __bf16* hn = (__bf16*)(ws);                    // [C][512][F]    8 MB
  __bf16* Y1 = (__bf16*)(ws + (8ULL << 20));     // [C][512][Fh]  32 MB
  __bf16* h2 = (__bf16*)(ws + (40ULL << 20));    // [Ch][512][Fh] 128 MB
  __bf16* Y2 = (__bf16*)(ws);                    // [Ch][F][512]  32 MB (reuse)

  (void)hipFuncSetAttribute((const void*)ln_kernel,
                            hipFuncAttributeMaxDynamicSharedMemorySize, 65792);
  (void)hipFuncSetAttribute((const void*)gemm_4p<5, true>,
                            hipFuncAttributeMaxDynamicSharedMemorySize, 163840);
  (void)hipFuncSetAttribute((const void*)gemm_4p<3, false>,
                            hipFuncAttributeMaxDynamicSharedMemorySize, 163840);

  ln_kernel<<<dim3(T_DIM / 16, C_DIM, B_DIM), 256, 65792, stream>>>(x, lnw, lnb, hn);
  // pw1: per c: [4096 x 1024] @ [1024 x 512]^T -> Y1^T [512][4096]
  gemm_4p<5, true><<<256, 512, 163840, stream>>>(pw1, hn, Y1, FH_DIM, F_DIM);
  mix1_kernel<<<(BT_DIM * (FH_DIM / 8)) / 256, 256, 0, stream>>>(Y1, dw1, h2);
  // pw2: per d: [1024 x 4096] @ [4096 x 512]^T -> Y2 [1024][512]
  gemm_4p<3, false><<<256, 512, 163840, stream>>>(pw2, h2, Y2, F_DIM, FH_DIM);
  mix2_kernel<<<512, 256, 0, stream>>>(x, Y2, dw2, out);
}